// Round 1
// baseline (403.814 us; speedup 1.0000x reference)
//
#include <hip/hip_runtime.h>

// _UnitDiscreteActionHead: out[b][n] (B x 6, f32) from
//   logits (24x24 f32), mask (B x 24 x 24 bool), conv (24x24 int32 in [0,6)).
// GEMM formulation: out16 = mask(B x 576) * W(576 x 16), W cols (bf16):
//   0..5: (conv==n)?bf16(logit):0   6..11: (conv==n-6)?1:0   12: 1   13..15: 0
// mfma_f32_16x16x32_bf16.
//
// R6 (fusion): single kernel. Weight table is built PER BLOCK in LDS in
// fragment-major order [frag][lane][8 bf16] so the inner-loop B read is a
// lane-consecutive ds_read_b128 (conflict-free; [n][k] layout would be a
// 16-way bank conflict since the 1152 B row stride is 0 mod 128).
// Removes: build_wt launch + inter-kernel gap, workspace flag/table global
// traffic. Mask dtype (u8 vs int32) detection unchanged in semantics:
// ballot over the first 256 mask dwords (int32 bools -> all <= 1).

typedef short bf16x8 __attribute__((ext_vector_type(8)));
typedef float f32x4 __attribute__((ext_vector_type(4)));
typedef unsigned uint4n __attribute__((ext_vector_type(4)));  // nt-load-able

union U4S8 { uint4n u; bf16x8 s; };

__device__ inline unsigned short f2bf(float f) {
  unsigned u = __builtin_bit_cast(unsigned, f);
  u += 0x7FFFu + ((u >> 16) & 1u);   // RNE
  return (unsigned short)(u >> 16);
}

// W[cell][n] as bf16 bits.
__device__ inline unsigned short wval(const float* __restrict__ logits,
                                      const int* __restrict__ conv,
                                      int cell, int n) {
  if (n > 12) return 0;
  if (n == 12) return 0x3F80;
  int g = conv[cell];
  if (n < 6) return (g == n) ? f2bf(logits[cell]) : (unsigned short)0;
  return (g == n - 6) ? (unsigned short)0x3F80 : (unsigned short)0;
}

// Two bf16 cells from one dword of mask bytes (LSB of each byte).
__device__ inline void cvt_pair(unsigned x, unsigned& lo, unsigned& hi) {
  lo = (x & 0x00010001u) * 0x3F80u;          // bf16(b0) | bf16(b2)<<16
  hi = ((x >> 8) & 0x00010001u) * 0x3F80u;   // bf16(b1) | bf16(b3)<<16
}

__global__ __launch_bounds__(256) void head_kernel(
    const float* __restrict__ logits,
    const unsigned char* __restrict__ mask,
    const int* __restrict__ conv,
    float* __restrict__ out,
    int ntiles) {
  // Fragment-major weight table: 18 frags x 64 lanes x 8 bf16 = 18 KiB.
  __shared__ __align__(16) unsigned short wt[18 * 64 * 8];
  __shared__ int votes[4];

  int tid = threadIdx.x;
  const unsigned* mask_dw = (const unsigned*)mask;

  // ---- dtype detection (same probe as R5: first 256 dwords of mask) ----
  // int32 bools -> all dwords <= 1; u8 bools -> random bytes make some > 1.
  unsigned long long bad = __ballot(mask_dw[tid] > 1u);
  if ((tid & 63) == 0) votes[tid >> 6] = (bad != 0ull);
  __syncthreads();
  int flag = !(votes[0] | votes[1] | votes[2] | votes[3]);  // 1 -> int32 path

  // ---- build LDS weight table for the detected path ----
  // Linear entry e = ((frag*64)+lane)*8 + j; coalesced u16 writes.
  if (flag) {
    // identity k-order: frag = kt (0..17); k = kt*32 + q*8 + j == cell
#pragma unroll 2
    for (int i = 0; i < 36; ++i) {
      int e = tid + i * 256;
      int j = e & 7, l = (e >> 3) & 63, kt = e >> 9;
      int cell = kt * 32 + (l >> 4) * 8 + j;
      wt[e] = wval(logits, conv, cell, l & 15);
    }
  } else {
    // u8 byte-pair order: frag = kt*2+which (0..17);
    // cell = kt*64 + q*16 + which*8 + p(j), p = {0,2,1,3,4,6,5,7}
#pragma unroll 2
    for (int i = 0; i < 36; ++i) {
      int e = tid + i * 256;
      int j = e & 7, l = (e >> 3) & 63, f = e >> 9;
      int pj = (j & 4) | ((j & 1) << 1) | ((j & 2) >> 1);
      int cell = (f >> 1) * 64 + (l >> 4) * 16 + (f & 1) * 8 + pj;
      wt[e] = wval(logits, conv, cell, l & 15);
    }
  }
  __syncthreads();

  int lane = tid & 63;
  int tile = blockIdx.x * 4 + (tid >> 6);   // one wave per 16-batch tile
  if (tile >= ntiles) return;

  int m = lane & 15;        // A: batch row within tile; B: output column n
  int q = lane >> 4;        // quad
  size_t tb = (size_t)tile * 16;
  const bf16x8* wl = (const bf16x8*)wt;     // ds_read_b128 at lane*16: no conflicts

  f32x4 acc = {0.f, 0.f, 0.f, 0.f};

  if (flag) {
    // ---- mask stored as int32 (one bool per dword), identity k-order ----
    const unsigned* mp = mask_dw + (tb + (size_t)m) * 576 + q * 8;
#pragma unroll 3
    for (int kt = 0; kt < 18; ++kt) {
      uint4n u = __builtin_nontemporal_load((const uint4n*)(mp + kt * 32));
      uint4n w = __builtin_nontemporal_load((const uint4n*)(mp + kt * 32 + 4));
      U4S8 a;
      a.u = (uint4n){(u.x | (u.y << 16)) * 0x3F80u,
                     (u.z | (u.w << 16)) * 0x3F80u,
                     (w.x | (w.y << 16)) * 0x3F80u,
                     (w.z | (w.w << 16)) * 0x3F80u};
      acc = __builtin_amdgcn_mfma_f32_16x16x32_bf16(a.s, wl[kt * 64 + lane],
                                                    acc, 0, 0, 0);
    }
  } else {
    // ---- mask stored as u8 bools, byte-pair-permuted k-order ----
    const unsigned char* ap = mask + (tb + (size_t)m) * 576 + q * 16;
#pragma unroll 3
    for (int kt = 0; kt < 9; ++kt) {
      uint4n av = __builtin_nontemporal_load((const uint4n*)(ap + kt * 64));
      U4S8 a0, a1;
      unsigned l0, h0, l1, h1;
      cvt_pair(av.x, l0, h0); cvt_pair(av.y, l1, h1);
      a0.u = (uint4n){l0, h0, l1, h1};
      cvt_pair(av.z, l0, h0); cvt_pair(av.w, l1, h1);
      a1.u = (uint4n){l0, h0, l1, h1};
      acc = __builtin_amdgcn_mfma_f32_16x16x32_bf16(a0.s, wl[(2 * kt) * 64 + lane],
                                                    acc, 0, 0, 0);
      acc = __builtin_amdgcn_mfma_f32_16x16x32_bf16(a1.s, wl[(2 * kt + 1) * 64 + lane],
                                                    acc, 0, 0, 0);
    }
  }

  // Epilogue. C/D layout: col(n) = lane&15, row(batch) = q*4 + r.
  int col = m;
  int srcCnt = (lane & 48) + ((col < 6) ? (col + 6) : 0);
  int srcTot = (lane & 48) + 12;
  float scale = (col == 5) ? (1.0f / 225.0f) : 1.0f;
  const float FMIN = -3.4028234663852886e38f;

#pragma unroll
  for (int r = 0; r < 4; ++r) {
    float s   = acc[r];
    float cnt = __shfl(s, srcCnt);
    float tot = __shfl(s, srcTot);
    if (col < 6) {
      float o;
      if (tot < 0.5f)       o = (col == 0) ? 1.0f : FMIN;
      else if (cnt > 0.5f)  o = s * scale;
      else                  o = FMIN;
      size_t b = tb + (size_t)q * 4 + r;
      out[b * 6 + col] = o;
    }
  }
}

extern "C" void kernel_launch(void* const* d_in, const int* in_sizes, int n_in,
                              void* d_out, int out_size, void* d_ws, size_t ws_size,
                              hipStream_t stream) {
  const float*          logits = (const float*)d_in[0];
  const unsigned char*  mask   = (const unsigned char*)d_in[1];
  const int*            conv   = (const int*)d_in[2];
  float*                out    = (float*)d_out;

  int B = in_sizes[1] / 576;       // 131072 (u8 layout, as in R5)
  int ntiles = B / 16;             // 8192
  int blocks = (ntiles + 3) / 4;   // 4 waves/block, one tile per wave

  head_kernel<<<blocks, 256, 0, stream>>>(logits, mask, conv, out, ntiles);
}

// Round 2
// 394.621 us; speedup vs baseline: 1.0233x; 1.0233x over previous
//
#include <hip/hip_runtime.h>

// _UnitDiscreteActionHead: out[b][n] (B x 6, f32) from
//   logits (24x24 f32), mask (B x 24 x 24 bool), conv (24x24 int32 in [0,6)).
// GEMM formulation: out16 = mask(B x 576) * W(576 x 16), W cols (bf16):
//   0..5: (conv==n)?bf16(logit):0   6..11: (conv==n-6)?1:0   12: 1   13..15: 0
// mfma_f32_16x16x32_bf16.
//
// R7: fused kernel, 2 tiles (32 batches) per wave.
//  - all 18 mask dwordx4 NT loads issued upfront into registers (18 KB/wave
//    in flight vs ~3 KB before) -> hide ~900cy HBM latency by ILP
//  - B-fragments (LDS) shared across the tile pair -> half the ds_reads/byte
//  - two independent acc chains -> MFMA ILP
//  - 1024 blocks (4/CU) instead of 2048 -> half the per-block table builds
// LDS weight table in fragment-major order [frag][lane][8 bf16]: inner-loop
// B read is a lane-consecutive ds_read_b128 (conflict-free).

typedef short bf16x8 __attribute__((ext_vector_type(8)));
typedef float f32x4 __attribute__((ext_vector_type(4)));
typedef unsigned uint4n __attribute__((ext_vector_type(4)));  // nt-load-able

union U4S8 { uint4n u; bf16x8 s; };

__device__ inline unsigned short f2bf(float f) {
  unsigned u = __builtin_bit_cast(unsigned, f);
  u += 0x7FFFu + ((u >> 16) & 1u);   // RNE
  return (unsigned short)(u >> 16);
}

// W[cell][n] as bf16 bits.
__device__ inline unsigned short wval(const float* __restrict__ logits,
                                      const int* __restrict__ conv,
                                      int cell, int n) {
  if (n > 12) return 0;
  if (n == 12) return 0x3F80;
  int g = conv[cell];
  if (n < 6) return (g == n) ? f2bf(logits[cell]) : (unsigned short)0;
  return (g == n - 6) ? (unsigned short)0x3F80 : (unsigned short)0;
}

// Two bf16 cells from one dword of mask bytes (LSB of each byte).
__device__ inline void cvt_pair(unsigned x, unsigned& lo, unsigned& hi) {
  lo = (x & 0x00010001u) * 0x3F80u;          // bf16(b0) | bf16(b2)<<16
  hi = ((x >> 8) & 0x00010001u) * 0x3F80u;   // bf16(b1) | bf16(b3)<<16
}

__global__ __launch_bounds__(256, 4) void head_kernel(
    const float* __restrict__ logits,
    const unsigned char* __restrict__ mask,
    const int* __restrict__ conv,
    float* __restrict__ out,
    int ntiles) {
  // Fragment-major weight table: 18 frags x 64 lanes x 8 bf16 = 18 KiB.
  __shared__ __align__(16) unsigned short wt[18 * 64 * 8];
  __shared__ int votes[4];

  int tid = threadIdx.x;
  const unsigned* mask_dw = (const unsigned*)mask;

  // ---- dtype detection (first 256 dwords of mask) ----
  // int32 bools -> all dwords <= 1; u8 bools -> random bytes make some > 1.
  unsigned long long bad = __ballot(mask_dw[tid] > 1u);
  if ((tid & 63) == 0) votes[tid >> 6] = (bad != 0ull);
  __syncthreads();
  int flag = !(votes[0] | votes[1] | votes[2] | votes[3]);  // 1 -> int32 path

  // ---- build LDS weight table for the detected path ----
  if (flag) {
    // identity k-order: frag = kt (0..17); k = kt*32 + q*8 + j == cell
#pragma unroll 2
    for (int i = 0; i < 36; ++i) {
      int e = tid + i * 256;
      int j = e & 7, l = (e >> 3) & 63, kt = e >> 9;
      int cell = kt * 32 + (l >> 4) * 8 + j;
      wt[e] = wval(logits, conv, cell, l & 15);
    }
  } else {
    // u8 byte-pair order: frag = kt*2+which (0..17);
    // cell = kt*64 + q*16 + which*8 + p(j), p = {0,2,1,3,4,6,5,7}
#pragma unroll 2
    for (int i = 0; i < 36; ++i) {
      int e = tid + i * 256;
      int j = e & 7, l = (e >> 3) & 63, f = e >> 9;
      int pj = (j & 4) | ((j & 1) << 1) | ((j & 2) >> 1);
      int cell = (f >> 1) * 64 + (l >> 4) * 16 + (f & 1) * 8 + pj;
      wt[e] = wval(logits, conv, cell, l & 15);
    }
  }
  __syncthreads();

  int lane = tid & 63;
  int t0 = (blockIdx.x * 4 + (tid >> 6)) * 2;   // first tile of this wave's pair
  if (t0 >= ntiles) return;
  bool two = (t0 + 1) < ntiles;                 // wave-uniform

  int m = lane & 15;        // A: batch row within tile; B: output column n
  int q = lane >> 4;        // quad
  size_t tb0 = (size_t)t0 * 16;
  const bf16x8* wl = (const bf16x8*)wt;  // ds_read_b128 at lane*16: no conflicts

  f32x4 acc0 = {0.f, 0.f, 0.f, 0.f};
  f32x4 acc1 = {0.f, 0.f, 0.f, 0.f};

  if (flag) {
    // ---- mask stored as int32 (one bool per dword), identity k-order ----
    const unsigned* mp0 = mask_dw + (tb0 + (size_t)m) * 576 + q * 8;
#pragma unroll 3
    for (int kt = 0; kt < 18; ++kt) {
      uint4n u = __builtin_nontemporal_load((const uint4n*)(mp0 + kt * 32));
      uint4n w = __builtin_nontemporal_load((const uint4n*)(mp0 + kt * 32 + 4));
      U4S8 a;
      a.u = (uint4n){(u.x | (u.y << 16)) * 0x3F80u,
                     (u.z | (u.w << 16)) * 0x3F80u,
                     (w.x | (w.y << 16)) * 0x3F80u,
                     (w.z | (w.w << 16)) * 0x3F80u};
      acc0 = __builtin_amdgcn_mfma_f32_16x16x32_bf16(a.s, wl[kt * 64 + lane],
                                                     acc0, 0, 0, 0);
    }
    if (two) {
      const unsigned* mp1 = mp0 + 16 * 576;
#pragma unroll 3
      for (int kt = 0; kt < 18; ++kt) {
        uint4n u = __builtin_nontemporal_load((const uint4n*)(mp1 + kt * 32));
        uint4n w = __builtin_nontemporal_load((const uint4n*)(mp1 + kt * 32 + 4));
        U4S8 a;
        a.u = (uint4n){(u.x | (u.y << 16)) * 0x3F80u,
                       (u.z | (u.w << 16)) * 0x3F80u,
                       (w.x | (w.y << 16)) * 0x3F80u,
                       (w.z | (w.w << 16)) * 0x3F80u};
        acc1 = __builtin_amdgcn_mfma_f32_16x16x32_bf16(a.s, wl[kt * 64 + lane],
                                                       acc1, 0, 0, 0);
      }
    }
  } else {
    // ---- mask stored as u8 bools, byte-pair-permuted k-order ----
    const unsigned char* ap0 = mask + (tb0 + (size_t)m) * 576 + q * 16;
    const unsigned char* ap1 = ap0 + 16 * 576;
    uint4n av0[9], av1[9];
#pragma unroll
    for (int kt = 0; kt < 9; ++kt)
      av0[kt] = __builtin_nontemporal_load((const uint4n*)(ap0 + kt * 64));
    if (two) {
#pragma unroll
      for (int kt = 0; kt < 9; ++kt)
        av1[kt] = __builtin_nontemporal_load((const uint4n*)(ap1 + kt * 64));
    }
#pragma unroll
    for (int kt = 0; kt < 9; ++kt) {
      bf16x8 b0 = wl[(2 * kt) * 64 + lane];
      bf16x8 b1 = wl[(2 * kt + 1) * 64 + lane];
      U4S8 a0, a1;
      unsigned l0, h0, l1, h1;
      cvt_pair(av0[kt].x, l0, h0); cvt_pair(av0[kt].y, l1, h1);
      a0.u = (uint4n){l0, h0, l1, h1};
      cvt_pair(av0[kt].z, l0, h0); cvt_pair(av0[kt].w, l1, h1);
      a1.u = (uint4n){l0, h0, l1, h1};
      acc0 = __builtin_amdgcn_mfma_f32_16x16x32_bf16(a0.s, b0, acc0, 0, 0, 0);
      acc0 = __builtin_amdgcn_mfma_f32_16x16x32_bf16(a1.s, b1, acc0, 0, 0, 0);
      if (two) {
        cvt_pair(av1[kt].x, l0, h0); cvt_pair(av1[kt].y, l1, h1);
        a0.u = (uint4n){l0, h0, l1, h1};
        cvt_pair(av1[kt].z, l0, h0); cvt_pair(av1[kt].w, l1, h1);
        a1.u = (uint4n){l0, h0, l1, h1};
        acc1 = __builtin_amdgcn_mfma_f32_16x16x32_bf16(a0.s, b0, acc1, 0, 0, 0);
        acc1 = __builtin_amdgcn_mfma_f32_16x16x32_bf16(a1.s, b1, acc1, 0, 0, 0);
      }
    }
  }

  // Epilogue. C/D layout: col(n) = lane&15, row(batch) = q*4 + r.
  int col = m;
  int srcCnt = (lane & 48) + ((col < 6) ? (col + 6) : 0);
  int srcTot = (lane & 48) + 12;
  float scale = (col == 5) ? (1.0f / 225.0f) : 1.0f;
  const float FMIN = -3.4028234663852886e38f;

#pragma unroll
  for (int r = 0; r < 4; ++r) {
    float s   = acc0[r];
    float cnt = __shfl(s, srcCnt);
    float tot = __shfl(s, srcTot);
    if (col < 6) {
      float o;
      if (tot < 0.5f)       o = (col == 0) ? 1.0f : FMIN;
      else if (cnt > 0.5f)  o = s * scale;
      else                  o = FMIN;
      size_t b = tb0 + (size_t)q * 4 + r;
      out[b * 6 + col] = o;
    }
  }
  if (two) {
#pragma unroll
    for (int r = 0; r < 4; ++r) {
      float s   = acc1[r];
      float cnt = __shfl(s, srcCnt);
      float tot = __shfl(s, srcTot);
      if (col < 6) {
        float o;
        if (tot < 0.5f)       o = (col == 0) ? 1.0f : FMIN;
        else if (cnt > 0.5f)  o = s * scale;
        else                  o = FMIN;
        size_t b = tb0 + 16 + (size_t)q * 4 + r;
        out[b * 6 + col] = o;
      }
    }
  }
}

extern "C" void kernel_launch(void* const* d_in, const int* in_sizes, int n_in,
                              void* d_out, int out_size, void* d_ws, size_t ws_size,
                              hipStream_t stream) {
  const float*          logits = (const float*)d_in[0];
  const unsigned char*  mask   = (const unsigned char*)d_in[1];
  const int*            conv   = (const int*)d_in[2];
  float*                out    = (float*)d_out;

  int B = in_sizes[1] / 576;       // 131072 (u8 layout)
  int ntiles = B / 16;             // 8192
  int npair = (ntiles + 1) / 2;    // tiles per wave = 2
  int blocks = (npair + 3) / 4;    // 4 waves/block -> 1024 blocks

  head_kernel<<<blocks, 256, 0, stream>>>(logits, mask, conv, out, ntiles);
}

// Round 3
// 392.363 us; speedup vs baseline: 1.0292x; 1.0058x over previous
//
#include <hip/hip_runtime.h>

// _UnitDiscreteActionHead: out[b][n] (B x 6, f32) from
//   logits (24x24 f32), mask (B x 24 x 24 bool), conv (24x24 int32 in [0,6)).
// GEMM formulation: out16 = mask(B x 576) * W(576 x 16), W cols (bf16):
//   0..5: (conv==n)?bf16(logit):0   6..11: (conv==n-6)?1:0   12: 1   13..15: 0
// mfma_f32_16x16x32_bf16.
//
// R8: 4 tiles (64 batches) per wave, single kernel.
//  - all 36 mask dwordx4 NT loads issued upfront (36 KB/wave in flight)
//  - inner loop interleaved over the 4 tiles: each B-fragment ds_read ONCE
//    per wave (18 total), 4 independent acc chains for MFMA ILP
//  - 512 blocks, __launch_bounds__(256,2): 8 waves/CU x 36 KB = 288 KB
//    outstanding per CU >> ~9 KB needed to cover HBM latency
// LDS weight table in fragment-major order [frag][lane][8 bf16]: inner-loop
// B read is a lane-consecutive ds_read_b128 (conflict-free).
// All acc/av arrays indexed only from fully-unrolled loops (stay in VGPRs).

typedef short bf16x8 __attribute__((ext_vector_type(8)));
typedef float f32x4 __attribute__((ext_vector_type(4)));
typedef unsigned uint4n __attribute__((ext_vector_type(4)));  // nt-load-able

union U4S8 { uint4n u; bf16x8 s; };

__device__ inline unsigned short f2bf(float f) {
  unsigned u = __builtin_bit_cast(unsigned, f);
  u += 0x7FFFu + ((u >> 16) & 1u);   // RNE
  return (unsigned short)(u >> 16);
}

// W[cell][n] as bf16 bits.
__device__ inline unsigned short wval(const float* __restrict__ logits,
                                      const int* __restrict__ conv,
                                      int cell, int n) {
  if (n > 12) return 0;
  if (n == 12) return 0x3F80;
  int g = conv[cell];
  if (n < 6) return (g == n) ? f2bf(logits[cell]) : (unsigned short)0;
  return (g == n - 6) ? (unsigned short)0x3F80 : (unsigned short)0;
}

// Two bf16 cells from one dword of mask bytes (LSB of each byte).
__device__ inline void cvt_pair(unsigned x, unsigned& lo, unsigned& hi) {
  lo = (x & 0x00010001u) * 0x3F80u;          // bf16(b0) | bf16(b2)<<16
  hi = ((x >> 8) & 0x00010001u) * 0x3F80u;   // bf16(b1) | bf16(b3)<<16
}

__global__ __launch_bounds__(256, 2) void head_kernel(
    const float* __restrict__ logits,
    const unsigned char* __restrict__ mask,
    const int* __restrict__ conv,
    float* __restrict__ out,
    int ntiles) {
  // Fragment-major weight table: 18 frags x 64 lanes x 8 bf16 = 18 KiB.
  __shared__ __align__(16) unsigned short wt[18 * 64 * 8];
  __shared__ int votes[4];

  int tid = threadIdx.x;
  const unsigned* mask_dw = (const unsigned*)mask;

  // ---- dtype detection (first 256 dwords of mask) ----
  // int32 bools -> all dwords <= 1; u8 bools -> random bytes make some > 1.
  unsigned long long bad = __ballot(mask_dw[tid] > 1u);
  if ((tid & 63) == 0) votes[tid >> 6] = (bad != 0ull);
  __syncthreads();
  int flag = !(votes[0] | votes[1] | votes[2] | votes[3]);  // 1 -> int32 path

  // ---- build LDS weight table for the detected path ----
  if (flag) {
    // identity k-order: frag = kt (0..17); k = kt*32 + q*8 + j == cell
#pragma unroll 2
    for (int i = 0; i < 36; ++i) {
      int e = tid + i * 256;
      int j = e & 7, l = (e >> 3) & 63, kt = e >> 9;
      int cell = kt * 32 + (l >> 4) * 8 + j;
      wt[e] = wval(logits, conv, cell, l & 15);
    }
  } else {
    // u8 byte-pair order: frag = kt*2+which (0..17);
    // cell = kt*64 + q*16 + which*8 + p(j), p = {0,2,1,3,4,6,5,7}
#pragma unroll 2
    for (int i = 0; i < 36; ++i) {
      int e = tid + i * 256;
      int j = e & 7, l = (e >> 3) & 63, f = e >> 9;
      int pj = (j & 4) | ((j & 1) << 1) | ((j & 2) >> 1);
      int cell = (f >> 1) * 64 + (l >> 4) * 16 + (f & 1) * 8 + pj;
      wt[e] = wval(logits, conv, cell, l & 15);
    }
  }
  __syncthreads();

  int lane = tid & 63;
  int t0 = (blockIdx.x * 4 + (tid >> 6)) * 4;   // first of this wave's 4 tiles
  if (t0 >= ntiles) return;

  int m = lane & 15;        // A: batch row within tile; B: output column n
  int q = lane >> 4;        // quad
  size_t tb0 = (size_t)t0 * 16;
  const bf16x8* wl = (const bf16x8*)wt;  // ds_read_b128 at lane*16: no conflicts

  f32x4 acc[4];
#pragma unroll
  for (int t = 0; t < 4; ++t) acc[t] = (f32x4){0.f, 0.f, 0.f, 0.f};

  if (flag) {
    // ---- mask stored as int32 (one bool per dword), identity k-order ----
#pragma unroll
    for (int t = 0; t < 4; ++t) {
      if (t0 + t >= ntiles) continue;            // wave-uniform
      const unsigned* mp = mask_dw + (tb0 + (size_t)t * 16 + (size_t)m) * 576 + q * 8;
#pragma unroll 3
      for (int kt = 0; kt < 18; ++kt) {
        uint4n u = __builtin_nontemporal_load((const uint4n*)(mp + kt * 32));
        uint4n w = __builtin_nontemporal_load((const uint4n*)(mp + kt * 32 + 4));
        U4S8 a;
        a.u = (uint4n){(u.x | (u.y << 16)) * 0x3F80u,
                       (u.z | (u.w << 16)) * 0x3F80u,
                       (w.x | (w.y << 16)) * 0x3F80u,
                       (w.z | (w.w << 16)) * 0x3F80u};
        acc[t] = __builtin_amdgcn_mfma_f32_16x16x32_bf16(a.s, wl[kt * 64 + lane],
                                                         acc[t], 0, 0, 0);
      }
    }
  } else {
    // ---- mask stored as u8 bools, byte-pair-permuted k-order ----
    const unsigned char* ap = mask + (tb0 + (size_t)m) * 576 + q * 16;
    uint4n av[4][9];
#pragma unroll
    for (int t = 0; t < 4; ++t) {
      if (t0 + t >= ntiles) continue;            // wave-uniform
#pragma unroll
      for (int kt = 0; kt < 9; ++kt)
        av[t][kt] = __builtin_nontemporal_load(
            (const uint4n*)(ap + t * 9216 + kt * 64));
    }
#pragma unroll
    for (int kt = 0; kt < 9; ++kt) {
      bf16x8 b0 = wl[(2 * kt) * 64 + lane];
      bf16x8 b1 = wl[(2 * kt + 1) * 64 + lane];
#pragma unroll
      for (int t = 0; t < 4; ++t) {
        if (t0 + t >= ntiles) continue;          // wave-uniform
        U4S8 a0, a1;
        unsigned l0, h0, l1, h1;
        cvt_pair(av[t][kt].x, l0, h0); cvt_pair(av[t][kt].y, l1, h1);
        a0.u = (uint4n){l0, h0, l1, h1};
        cvt_pair(av[t][kt].z, l0, h0); cvt_pair(av[t][kt].w, l1, h1);
        a1.u = (uint4n){l0, h0, l1, h1};
        acc[t] = __builtin_amdgcn_mfma_f32_16x16x32_bf16(a0.s, b0, acc[t], 0, 0, 0);
        acc[t] = __builtin_amdgcn_mfma_f32_16x16x32_bf16(a1.s, b1, acc[t], 0, 0, 0);
      }
    }
  }

  // Epilogue. C/D layout: col(n) = lane&15, row(batch) = q*4 + r.
  int col = m;
  int srcCnt = (lane & 48) + ((col < 6) ? (col + 6) : 0);
  int srcTot = (lane & 48) + 12;
  float scale = (col == 5) ? (1.0f / 225.0f) : 1.0f;
  const float FMIN = -3.4028234663852886e38f;

#pragma unroll
  for (int t = 0; t < 4; ++t) {
    if (t0 + t >= ntiles) continue;              // wave-uniform
#pragma unroll
    for (int r = 0; r < 4; ++r) {
      float s   = acc[t][r];
      float cnt = __shfl(s, srcCnt);
      float tot = __shfl(s, srcTot);
      if (col < 6) {
        float o;
        if (tot < 0.5f)       o = (col == 0) ? 1.0f : FMIN;
        else if (cnt > 0.5f)  o = s * scale;
        else                  o = FMIN;
        size_t b = tb0 + (size_t)t * 16 + (size_t)q * 4 + r;
        out[b * 6 + col] = o;
      }
    }
  }
}

extern "C" void kernel_launch(void* const* d_in, const int* in_sizes, int n_in,
                              void* d_out, int out_size, void* d_ws, size_t ws_size,
                              hipStream_t stream) {
  const float*          logits = (const float*)d_in[0];
  const unsigned char*  mask   = (const unsigned char*)d_in[1];
  const int*            conv   = (const int*)d_in[2];
  float*                out    = (float*)d_out;

  int B = in_sizes[1] / 576;       // 131072 (u8 layout)
  int ntiles = B / 16;             // 8192
  int blocks = (ntiles + 15) / 16; // 4 waves/block x 4 tiles/wave -> 512 blocks

  head_kernel<<<blocks, 256, 0, stream>>>(logits, mask, conv, out, ntiles);
}